// Round 10
// baseline (256.280 us; speedup 1.0000x reference)
//
#include <hip/hip_runtime.h>
#include <math.h>

#define CC 64
#define HWN 4096
#define QB 64            // q per block; ALL 16 waves compute the same 64 q
#define KSPLIT 16        // each wave privately owns 256 k
#define KT 32
#define NITER (HWN / KSPLIT / KT)   // 8 chunks per wave
#define NKC (HWN / KT)              // 128 k-chunks per batch

typedef __attribute__((ext_vector_type(8))) short bf16x8;
typedef __attribute__((ext_vector_type(4))) short bf16x4;
typedef __attribute__((ext_vector_type(4))) float f32x4;

// precomputed bf16 operand layouts (written by prep_kernel every launch)
__device__ __align__(16) unsigned short g_bgT[4][HWN][CC];       // (bg*sb)^T [b][k][c]
__device__ __align__(16) unsigned short g_bgN[4][NKC][CC][KT];   // bf16(bg) chunk-major
__device__ __align__(16) unsigned short g_fgT[4][HWN][CC];       // (fg*sf)^T [b][q][c]

static __device__ __forceinline__ unsigned int f2bf(float x) {   // RNE
  union { float f; unsigned int u; } v; v.f = x;
  return (v.u + 0x7fffu + ((v.u >> 16) & 1u)) >> 16;
}
static __device__ __forceinline__ unsigned int packbf(float lo, float hi) {
  return f2bf(lo) | (f2bf(hi) << 16);
}

// ---- prep: fused column norms + bf16 operand layouts (identical to r8/r9) ----
// grid 512 = which(2) x b(4) x ktile(64), 256 threads
__global__ __launch_bounds__(256) void prep_kernel(const float* __restrict__ bg,
                                                   const float* __restrict__ fg) {
  __shared__ float lds[64 * 65];   // [k][c], stride 65 (2-way banks everywhere)
  const int bid = blockIdx.x;
  const int kt = bid & 63, b = (bid >> 6) & 3, which = bid >> 8;
  const float* src = (which ? fg : bg) + (size_t)b * CC * HWN + kt * 64;
  const int tid = threadIdx.x;

  // stage tile transposed: thread loads [c][k-range] float4, writes lds[k][c]
  {
    int c = tid >> 2, k0 = (tid & 3) * 16;
#pragma unroll
    for (int j4 = 0; j4 < 4; ++j4) {
      float4 v = *(const float4*)(src + (size_t)c * HWN + k0 + 4 * j4);
      lds[(k0 + 4 * j4 + 0) * 65 + c] = v.x;
      lds[(k0 + 4 * j4 + 1) * 65 + c] = v.y;
      lds[(k0 + 4 * j4 + 2) * 65 + c] = v.z;
      lds[(k0 + 4 * j4 + 3) * 65 + c] = v.w;
    }
  }
  __syncthreads();

  const int k = tid >> 2, u = tid & 3;
  // column norm: 4 threads per k, each sums 16 c, combine via shfl
  float ss = 0.f;
#pragma unroll
  for (int j = 0; j < 16; ++j) {
    float v = lds[k * 65 + u * 16 + j];
    ss = fmaf(v, v, ss);
  }
  ss += __shfl_xor(ss, 1, 64);
  ss += __shfl_xor(ss, 2, 64);
  const float s = 1.0f / fmaxf(sqrtf(ss), 1e-12f);

  // write scaled transposed [b][k][c] bf16
  {
    unsigned int* gT32 = (unsigned int*)(which ? &g_fgT[0][0][0] : &g_bgT[0][0][0]);
    size_t R = (size_t)b * HWN + kt * 64 + k;
    unsigned int w8[8];
#pragma unroll
    for (int i = 0; i < 8; ++i) {
      int c2 = u * 16 + 2 * i;
      w8[i] = packbf(lds[k * 65 + c2] * s, lds[k * 65 + c2 + 1] * s);
    }
    *(uint4*)&gT32[R * 32 + u * 8]     = make_uint4(w8[0], w8[1], w8[2], w8[3]);
    *(uint4*)&gT32[R * 32 + u * 8 + 4] = make_uint4(w8[4], w8[5], w8[6], w8[7]);
  }

  // bg blocks also write raw cast, chunk-major: [b][kc][c][32]
  if (which == 0) {
    unsigned int* gN32 = (unsigned int*)&g_bgN[0][0][0][0];
    int cN = tid >> 2, vN = tid & 3;   // vN covers k = vN*16 .. +15 of this 64-k tile
    unsigned int n8[8];
#pragma unroll
    for (int i = 0; i < 8; ++i) {
      int kk = vN * 16 + 2 * i;
      n8[i] = packbf(lds[kk * 65 + cN], lds[(kk + 1) * 65 + cN]);
    }
    int kc = kt * 2 + (vN >> 1);           // global chunk index within batch
    size_t RN = (((size_t)b * NKC + kc) * CC + cN) * (KT / 2) + (vN & 1) * 8;
    *(uint4*)&gN32[RN]     = make_uint4(n8[0], n8[1], n8[2], n8[3]);
    *(uint4*)&gN32[RN + 4] = make_uint4(n8[4], n8[5], n8[6], n8[7]);
  }
}

// ---- flash attention: all-register loop at 4 waves/SIMD ----
// r9 measured: 45% stall at 2 waves/SIMD, traffic L2-resident (FETCH 7.3MB),
// no LDS/barriers in loop -> naked dependent-chain latency. Fix: 1024-thread
// blocks, KSPLIT 16 (wave owns 256 k) -> SAME q-tile per block (traffic
// unchanged, r4 trap avoided), 16 waves/CU = 4/SIMD. VGPR 116 fits the
// 128-reg budget of __launch_bounds__(1024,4).
// LDS (epilogue only): [0,69632) mO [16ks][64c][17q] f32 (4 q-passes of 16)
//                      [69632,73728) mL [16ks][64q] f32
#define ML_OFF 69632
#define SMEM_BYTES 73728
__global__ __launch_bounds__(1024, 4) void attn_kernel(const float* __restrict__ fg,
                                                       const float* __restrict__ mask,
                                                       float* __restrict__ out) {
  __shared__ __align__(16) char smem[SMEM_BYTES];
  // bijective XCD swizzle (256 % 8 == 0): 2 XCDs per batch -> 2MB working set/L2
  const int wg = blockIdx.x;
  const int wgp = (wg & 7) * 32 + (wg >> 3);
  const int b = wgp >> 6;
  const int q0 = (wgp & 63) * QB;
  const int tid = threadIdx.x;
  const int lane = tid & 63;
  const int ks = tid >> 6;    // 0..15, private K-split (256 k each)
  const int m16 = lane & 15;
  const int quad = lane >> 4;

  // fg B-fragments (64 q), loaded once from global (L2)
  bf16x8 Bf[4][2];
#pragma unroll
  for (int qf = 0; qf < 4; ++qf)
#pragma unroll
    for (int h = 0; h < 2; ++h)
      Bf[qf][h] = *(const bf16x8*)&g_fgT[b][q0 + qf * 16 + m16][h * 32 + quad * 8];

  const unsigned short* const baseT = &g_bgT[b][ks * 256][0];      // row stride 64
  const unsigned short* const baseN = &g_bgN[b][ks * 8][0][0];     // 4KB blocks

  float* mL = (float*)(smem + ML_OFF);

  float l_run[4] = {0.f, 0.f, 0.f, 0.f};   // per-lane partial sums per q-frag
  f32x4 O[4][4];                            // [c-tile][q-frag]
#pragma unroll
  for (int t = 0; t < 4; ++t)
#pragma unroll
    for (int qf = 0; qf < 4; ++qf) O[t][qf] = (f32x4){0.f, 0.f, 0.f, 0.f};

  // register loads for one chunk: QK A-frags (2 k-rows x 2 c-halves) + PV A-frags
  auto loadT = [&](bf16x8 (&T)[2][2], int ch) {
#pragma unroll
    for (int i = 0; i < 2; ++i)
#pragma unroll
      for (int h = 0; h < 2; ++h)
        T[i][h] = *(const bf16x8*)(baseT + (size_t)(ch * 32 + i * 16 + m16) * CC +
                                   h * 32 + quad * 8);
  };
  auto loadA = [&](bf16x4 (&A)[4][2], int ch) {
#pragma unroll
    for (int ct = 0; ct < 4; ++ct)
#pragma unroll
      for (int i = 0; i < 2; ++i)
        A[ct][i] = *(const bf16x4*)(baseN + (size_t)ch * (CC * KT) +
                                    (ct * 16 + m16) * KT + i * 16 + quad * 4);
  };

  bf16x8 Ta[2][2], Tb[2][2];
  bf16x4 Aa[4][2], Ab[4][2];

  // one pipeline step: compute chunk `it` from regs T/A, prefetch it+1 into Tn/An
  auto iter = [&](int it, bf16x8 (&T)[2][2], bf16x4 (&A)[4][2],
                  bf16x8 (&Tn)[2][2], bf16x4 (&An)[4][2]) {
    if (it + 1 < NITER) {
      loadT(Tn, it + 1);     // 4 x 16B
      loadA(An, it + 1);     // 8 x 8B
      // oldest-12 wait: chunk-it's 12 loads complete; 12 newer stay in flight
      asm volatile("s_waitcnt vmcnt(12)" ::: "memory");
    } else {
      asm volatile("s_waitcnt vmcnt(0)" ::: "memory");
    }

    // QK: S[32k][64q] = (bg*sb)^T · (fg*sf)   (all-register, K=32 MFMA)
    f32x4 S[4][2];
    __builtin_amdgcn_s_setprio(1);
#pragma unroll
    for (int i = 0; i < 2; ++i)
#pragma unroll
      for (int qf = 0; qf < 4; ++qf) {
        f32x4 acc = {0.f, 0.f, 0.f, 0.f};
        acc = __builtin_amdgcn_mfma_f32_16x16x32_bf16(T[i][0], Bf[qf][0], acc, 0, 0, 0);
        acc = __builtin_amdgcn_mfma_f32_16x16x32_bf16(T[i][1], Bf[qf][1], acc, 0, 0, 0);
        S[qf][i] = acc;
      }
    __builtin_amdgcn_s_setprio(0);

    // fixed-max softmax: cosines, |s| <= 1 -> p = exp(s-1); pack pairs to bf16.
    // Packed regs ARE the PV B-fragments (K=16 layout match), no LDS roundtrip.
    bf16x4 Pp[4][2];
#pragma unroll
    for (int qf = 0; qf < 4; ++qf)
#pragma unroll
      for (int i = 0; i < 2; ++i) {
        float pe[4];
#pragma unroll
        for (int r = 0; r < 4; ++r) {
          pe[r] = __expf(S[qf][i][r] - 1.0f);
          l_run[qf] += pe[r];
        }
        union { float f; unsigned int u; } x0, x1, x2, x3;
        x0.f = pe[0]; x1.f = pe[1]; x2.f = pe[2]; x3.f = pe[3];
        union { unsigned int u[2]; bf16x4 v; } pk;
        pk.u[0] = __builtin_amdgcn_perm(x1.u + 0x8000u, x0.u + 0x8000u, 0x07060302u);
        pk.u[1] = __builtin_amdgcn_perm(x3.u + 0x8000u, x2.u + 0x8000u, 0x07060302u);
        Pp[qf][i] = pk.v;
      }

    // PV: O[c][q] += bg[c][k] · P[k][q]  via 2x K=16 MFMA per (ct,qf), all-register
    __builtin_amdgcn_s_setprio(1);
#pragma unroll
    for (int ct = 0; ct < 4; ++ct)
#pragma unroll
      for (int qf = 0; qf < 4; ++qf) {
        O[ct][qf] = __builtin_amdgcn_mfma_f32_16x16x16bf16_1k(A[ct][0], Pp[qf][0],
                                                              O[ct][qf], 0, 0, 0);
        O[ct][qf] = __builtin_amdgcn_mfma_f32_16x16x16bf16_1k(A[ct][1], Pp[qf][1],
                                                              O[ct][qf], 0, 0, 0);
      }
    __builtin_amdgcn_s_setprio(0);
  };

  // prologue: chunk 0 in flight (12 loads)
  loadT(Ta, 0);
  loadA(Aa, 0);

  for (int it2 = 0; it2 < NITER; it2 += 2) {
    iter(it2,     Ta, Aa, Tb, Ab);
    iter(it2 + 1, Tb, Ab, Ta, Aa);
  }

  // ---- merge 16 K-splits + epilogue (four q-passes of 16; mO in LDS) ----
#pragma unroll
  for (int qf = 0; qf < 4; ++qf) {
    l_run[qf] += __shfl_xor(l_run[qf], 16, 64);
    l_run[qf] += __shfl_xor(l_run[qf], 32, 64);
  }
  if (quad == 0) {
#pragma unroll
    for (int qf = 0; qf < 4; ++qf) mL[ks * 64 + qf * 16 + m16] = l_run[qf];
  }
  float* mO = (float*)smem;   // [16 ks][64 c][17]
  const float* fgB = fg + (size_t)b * CC * HWN;
  const float* mk = mask + (size_t)b * HWN;
  float* outB = out + (size_t)b * CC * HWN;

#pragma unroll
  for (int p = 0; p < 4; ++p) {
    // write this pass's partials (per-ks-private region; no pre-barrier needed:
    // pass p-1's reads completed behind the trailing barrier)
#pragma unroll
    for (int t = 0; t < 4; ++t)
#pragma unroll
      for (int r = 0; r < 4; ++r)
        mO[(ks * 64 + 16 * t + quad * 4 + r) * 17 + m16] = O[t][p][r];
    __syncthreads();
    {
      int q = tid & 15, c = tid >> 4;   // 1024 threads = 64 c x 16 q
      int qglob = q0 + p * 16 + q;
      float L = 0.f;
#pragma unroll
      for (int s = 0; s < 16; ++s) L += mL[s * 64 + p * 16 + q];
      float acc = 0.f;
#pragma unroll
      for (int s = 0; s < 16; ++s) acc += mO[(s * 64 + c) * 17 + q];
      float att = acc / L;
      float mv = mk[qglob];
      float fgv = fgB[(size_t)c * HWN + qglob];
      outB[(size_t)c * HWN + qglob] = fgv + mv * (att - fgv);
    }
    __syncthreads();
  }
}

extern "C" void kernel_launch(void* const* d_in, const int* in_sizes, int n_in,
                              void* d_out, int out_size, void* d_ws, size_t ws_size,
                              hipStream_t stream) {
  const float* background = (const float*)d_in[0];
  const float* foreground = (const float*)d_in[1];
  const float* mask       = (const float*)d_in[2];
  float* out = (float*)d_out;
  prep_kernel<<<512, 256, 0, stream>>>(background, foreground);
  attn_kernel<<<dim3(HWN / QB * 4), 1024, 0, stream>>>(foreground, mask, out);
}

// Round 11
// 128.696 us; speedup vs baseline: 1.9914x; 1.9914x over previous
//
#include <hip/hip_runtime.h>
#include <math.h>

#define CC 64
#define HWN 4096
#define QB 64            // q per block; 16 waves = 2 q-halves x 8 K-splits
#define KSPLIT 8         // per q-half; each wave owns 512 k
#define KT 32
#define NITER (HWN / KSPLIT / KT)   // 16 chunks per wave
#define NKC (HWN / KT)              // 128 k-chunks per batch

typedef __attribute__((ext_vector_type(8))) short bf16x8;
typedef __attribute__((ext_vector_type(4))) short bf16x4;
typedef __attribute__((ext_vector_type(4))) float f32x4;

// precomputed bf16 operand layouts (written by prep_kernel every launch)
__device__ __align__(16) unsigned short g_bgT[4][HWN][CC];       // (bg*sb)^T [b][k][c]
__device__ __align__(16) unsigned short g_bgN[4][NKC][CC][KT];   // bf16(bg) chunk-major
__device__ __align__(16) unsigned short g_fgT[4][HWN][CC];       // (fg*sf)^T [b][q][c]

static __device__ __forceinline__ unsigned int f2bf(float x) {   // RNE
  union { float f; unsigned int u; } v; v.f = x;
  return (v.u + 0x7fffu + ((v.u >> 16) & 1u)) >> 16;
}
static __device__ __forceinline__ unsigned int packbf(float lo, float hi) {
  return f2bf(lo) | (f2bf(hi) << 16);
}

// ---- prep: fused column norms + bf16 operand layouts (identical to r8/r9) ----
// grid 512 = which(2) x b(4) x ktile(64), 256 threads
__global__ __launch_bounds__(256) void prep_kernel(const float* __restrict__ bg,
                                                   const float* __restrict__ fg) {
  __shared__ float lds[64 * 65];   // [k][c], stride 65 (2-way banks everywhere)
  const int bid = blockIdx.x;
  const int kt = bid & 63, b = (bid >> 6) & 3, which = bid >> 8;
  const float* src = (which ? fg : bg) + (size_t)b * CC * HWN + kt * 64;
  const int tid = threadIdx.x;

  // stage tile transposed: thread loads [c][k-range] float4, writes lds[k][c]
  {
    int c = tid >> 2, k0 = (tid & 3) * 16;
#pragma unroll
    for (int j4 = 0; j4 < 4; ++j4) {
      float4 v = *(const float4*)(src + (size_t)c * HWN + k0 + 4 * j4);
      lds[(k0 + 4 * j4 + 0) * 65 + c] = v.x;
      lds[(k0 + 4 * j4 + 1) * 65 + c] = v.y;
      lds[(k0 + 4 * j4 + 2) * 65 + c] = v.z;
      lds[(k0 + 4 * j4 + 3) * 65 + c] = v.w;
    }
  }
  __syncthreads();

  const int k = tid >> 2, u = tid & 3;
  // column norm: 4 threads per k, each sums 16 c, combine via shfl
  float ss = 0.f;
#pragma unroll
  for (int j = 0; j < 16; ++j) {
    float v = lds[k * 65 + u * 16 + j];
    ss = fmaf(v, v, ss);
  }
  ss += __shfl_xor(ss, 1, 64);
  ss += __shfl_xor(ss, 2, 64);
  const float s = 1.0f / fmaxf(sqrtf(ss), 1e-12f);

  // write scaled transposed [b][k][c] bf16
  {
    unsigned int* gT32 = (unsigned int*)(which ? &g_fgT[0][0][0] : &g_bgT[0][0][0]);
    size_t R = (size_t)b * HWN + kt * 64 + k;
    unsigned int w8[8];
#pragma unroll
    for (int i = 0; i < 8; ++i) {
      int c2 = u * 16 + 2 * i;
      w8[i] = packbf(lds[k * 65 + c2] * s, lds[k * 65 + c2 + 1] * s);
    }
    *(uint4*)&gT32[R * 32 + u * 8]     = make_uint4(w8[0], w8[1], w8[2], w8[3]);
    *(uint4*)&gT32[R * 32 + u * 8 + 4] = make_uint4(w8[4], w8[5], w8[6], w8[7]);
  }

  // bg blocks also write raw cast, chunk-major: [b][kc][c][32]
  if (which == 0) {
    unsigned int* gN32 = (unsigned int*)&g_bgN[0][0][0][0];
    int cN = tid >> 2, vN = tid & 3;   // vN covers k = vN*16 .. +15 of this 64-k tile
    unsigned int n8[8];
#pragma unroll
    for (int i = 0; i < 8; ++i) {
      int kk = vN * 16 + 2 * i;
      n8[i] = packbf(lds[kk * 65 + cN], lds[(kk + 1) * 65 + cN]);
    }
    int kc = kt * 2 + (vN >> 1);           // global chunk index within batch
    size_t RN = (((size_t)b * NKC + kc) * CC + cN) * (KT / 2) + (vN & 1) * 8;
    *(uint4*)&gN32[RN]     = make_uint4(n8[0], n8[1], n8[2], n8[3]);
    *(uint4*)&gN32[RN + 4] = make_uint4(n8[4], n8[5], n8[6], n8[7]);
  }
}

// ---- flash attention: all-register loop, 4 waves/SIMD, <=128-reg wave state ----
// r10 lesson: r9's true state ~180 regs (incl. AGPR) can't fit the 128-reg
// budget 4 waves/SIMD requires -> forced cap spilled (586MB scratch writes).
// This round: 16 waves = 2 q-halves(32q) x 8 K-splits; per-wave state shrinks
// to ~115 regs (Bf 16, O 32, T 16, A 16, transients). T/A are SINGLE-buffered
// with prefetch-after-last-use (loadT(it+1) reuses T's regs right after QK;
// loadA(it+1) after PV); counted vmcnt(8)/vmcnt(4) keep prefetch in flight.
// Same 64-q block tile -> staged footprint unchanged (q-half duplicate reads
// are same-CU, L1/L2-served). __launch_bounds__(1024) (no 2nd arg): 16-wave
// residency auto-caps regs at 128 without r10's mis-cap.
// LDS (epilogue only): [0,69632) mO [8ks][64c][34q] f32 (2 q-half passes)
//                      [69632,71680) mL [8ks][64q] f32
#define ML_OFF 69632
#define SMEM_BYTES 71680
__global__ __launch_bounds__(1024) void attn_kernel(const float* __restrict__ fg,
                                                    const float* __restrict__ mask,
                                                    float* __restrict__ out) {
  __shared__ __align__(16) char smem[SMEM_BYTES];
  // bijective XCD swizzle (256 % 8 == 0): 2 XCDs per batch -> 2MB working set/L2
  const int wg = blockIdx.x;
  const int wgp = (wg & 7) * 32 + (wg >> 3);
  const int b = wgp >> 6;
  const int q0 = (wgp & 63) * QB;
  const int tid = threadIdx.x;
  const int lane = tid & 63;
  const int w = tid >> 6;     // 0..15
  const int qg = w & 1;       // q-half (32 q)
  const int ks = w >> 1;      // 0..7, private K-split (512 k each)
  const int m16 = lane & 15;
  const int quad = lane >> 4;

  // fg B-fragments (this wave's 32 q), loaded once from global (L2)
  bf16x8 Bf[2][2];
#pragma unroll
  for (int qf = 0; qf < 2; ++qf)
#pragma unroll
    for (int h = 0; h < 2; ++h)
      Bf[qf][h] = *(const bf16x8*)&g_fgT[b][q0 + qg * 32 + qf * 16 + m16][h * 32 + quad * 8];

  const unsigned short* const baseT = &g_bgT[b][ks * 512][0];      // row stride 64
  const unsigned short* const baseN = &g_bgN[b][ks * 16][0][0];    // 4KB blocks

  float* mL = (float*)(smem + ML_OFF);

  float l_run[2] = {0.f, 0.f};   // per-lane partial sums per q-frag
  f32x4 O[4][2];                  // [c-tile][q-frag]
#pragma unroll
  for (int t = 0; t < 4; ++t)
#pragma unroll
    for (int qf = 0; qf < 2; ++qf) O[t][qf] = (f32x4){0.f, 0.f, 0.f, 0.f};

  // single-buffered chunk operands (prefetch-after-last-use reuses these regs)
  bf16x8 T[2][2];   // QK A-frags: [k-row i][c-half h]
  bf16x4 A[4][2];   // PV A-frags: [c-tile ct][k-half i]

  auto loadT = [&](int ch) {
#pragma unroll
    for (int i = 0; i < 2; ++i)
#pragma unroll
      for (int h = 0; h < 2; ++h)
        T[i][h] = *(const bf16x8*)(baseT + (size_t)(ch * 32 + i * 16 + m16) * CC +
                                   h * 32 + quad * 8);
  };
  auto loadA = [&](int ch) {
#pragma unroll
    for (int ct = 0; ct < 4; ++ct)
#pragma unroll
      for (int i = 0; i < 2; ++i)
        A[ct][i] = *(const bf16x4*)(baseN + (size_t)ch * (CC * KT) +
                                    (ct * 16 + m16) * KT + i * 16 + quad * 4);
  };

  // prologue: chunk 0 in flight (4 T-loads then 8 A-loads)
  loadT(0);
  loadA(0);

  for (int it = 0; it < NITER; ++it) {
    // T(it) ready (8 newer A(it) stay outstanding)
    asm volatile("s_waitcnt vmcnt(8)" ::: "memory");

    // QK: S[32k][32q] = (bg*sb)^T · (fg*sf)   (all-register, K=32 MFMA)
    f32x4 S[2][2];
    __builtin_amdgcn_s_setprio(1);
#pragma unroll
    for (int i = 0; i < 2; ++i)
#pragma unroll
      for (int qf = 0; qf < 2; ++qf) {
        f32x4 acc = {0.f, 0.f, 0.f, 0.f};
        acc = __builtin_amdgcn_mfma_f32_16x16x32_bf16(T[i][0], Bf[qf][0], acc, 0, 0, 0);
        acc = __builtin_amdgcn_mfma_f32_16x16x32_bf16(T[i][1], Bf[qf][1], acc, 0, 0, 0);
        S[qf][i] = acc;
      }
    __builtin_amdgcn_s_setprio(0);

    // T regs dead -> prefetch next chunk's T into the same registers
    if (it + 1 < NITER) loadT(it + 1);

    // fixed-max softmax: cosines, |s| <= 1 -> p = exp(s-1); pack pairs to bf16.
    // Packed regs ARE the PV B-fragments (K=16 layout match), no LDS roundtrip.
    bf16x4 Pp[2][2];
#pragma unroll
    for (int qf = 0; qf < 2; ++qf)
#pragma unroll
      for (int i = 0; i < 2; ++i) {
        float pe[4];
#pragma unroll
        for (int r = 0; r < 4; ++r) {
          pe[r] = __expf(S[qf][i][r] - 1.0f);
          l_run[qf] += pe[r];
        }
        union { float f; unsigned int u; } x0, x1, x2, x3;
        x0.f = pe[0]; x1.f = pe[1]; x2.f = pe[2]; x3.f = pe[3];
        union { unsigned int u[2]; bf16x4 v; } pk;
        pk.u[0] = __builtin_amdgcn_perm(x1.u + 0x8000u, x0.u + 0x8000u, 0x07060302u);
        pk.u[1] = __builtin_amdgcn_perm(x3.u + 0x8000u, x2.u + 0x8000u, 0x07060302u);
        Pp[qf][i] = pk.v;
      }

    // A(it) ready (leave next T's 4 loads outstanding)
    if (it + 1 < NITER) {
      asm volatile("s_waitcnt vmcnt(4)" ::: "memory");
    } else {
      asm volatile("s_waitcnt vmcnt(0)" ::: "memory");
    }

    // PV: O[c][q] += bg[c][k] · P[k][q]  via 2x K=16 MFMA per (ct,qf)
    __builtin_amdgcn_s_setprio(1);
#pragma unroll
    for (int ct = 0; ct < 4; ++ct)
#pragma unroll
      for (int qf = 0; qf < 2; ++qf) {
        O[ct][qf] = __builtin_amdgcn_mfma_f32_16x16x16bf16_1k(A[ct][0], Pp[qf][0],
                                                              O[ct][qf], 0, 0, 0);
        O[ct][qf] = __builtin_amdgcn_mfma_f32_16x16x16bf16_1k(A[ct][1], Pp[qf][1],
                                                              O[ct][qf], 0, 0, 0);
      }
    __builtin_amdgcn_s_setprio(0);

    // A regs dead -> prefetch next chunk's A
    if (it + 1 < NITER) loadA(it + 1);
  }

  // ---- merge 8 K-splits + epilogue (two q-half passes; mO in LDS) ----
#pragma unroll
  for (int qf = 0; qf < 2; ++qf) {
    l_run[qf] += __shfl_xor(l_run[qf], 16, 64);
    l_run[qf] += __shfl_xor(l_run[qf], 32, 64);
  }
  if (quad == 0) {
#pragma unroll
    for (int qf = 0; qf < 2; ++qf) mL[ks * 64 + qg * 32 + qf * 16 + m16] = l_run[qf];
  }
  float* mO = (float*)smem;   // [8 ks][64 c][34]
  const float* fgB = fg + (size_t)b * CC * HWN;
  const float* mk = mask + (size_t)b * HWN;
  float* outB = out + (size_t)b * CC * HWN;

#pragma unroll
  for (int half = 0; half < 2; ++half) {
    __syncthreads();   // pass 0: mL visible; pass 1: prior reads done before overwrite
    if (qg == half) {
#pragma unroll
      for (int qf = 0; qf < 2; ++qf)
#pragma unroll
        for (int t = 0; t < 4; ++t)
#pragma unroll
          for (int r = 0; r < 4; ++r)
            mO[(ks * 64 + 16 * t + quad * 4 + r) * 34 + qf * 16 + m16] = O[t][qf][r];
    }
    __syncthreads();
    {
      int q = tid & 31, cb = tid >> 5;   // cb 0..31
      int qglob = q0 + half * 32 + q;
      float L = 0.f;
#pragma unroll
      for (int s = 0; s < 8; ++s) L += mL[s * 64 + half * 32 + q];
      float invL = 1.0f / L;
      float mv = mk[qglob];
#pragma unroll
      for (int e = 0; e < 2; ++e) {
        int c = cb * 2 + e;
        float acc = 0.f;
#pragma unroll
        for (int s = 0; s < 8; ++s) acc += mO[(s * 64 + c) * 34 + q];
        float att = acc * invL;
        float fgv = fgB[(size_t)c * HWN + qglob];
        outB[(size_t)c * HWN + qglob] = fgv + mv * (att - fgv);
      }
    }
  }
}

extern "C" void kernel_launch(void* const* d_in, const int* in_sizes, int n_in,
                              void* d_out, int out_size, void* d_ws, size_t ws_size,
                              hipStream_t stream) {
  const float* background = (const float*)d_in[0];
  const float* foreground = (const float*)d_in[1];
  const float* mask       = (const float*)d_in[2];
  float* out = (float*)d_out;
  prep_kernel<<<512, 256, 0, stream>>>(background, foreground);
  attn_kernel<<<dim3(HWN / QB * 4), 1024, 0, stream>>>(foreground, mask, out);
}

// Round 12
// 93.590 us; speedup vs baseline: 2.7383x; 1.3751x over previous
//
#include <hip/hip_runtime.h>
#include <math.h>

#define CC 64
#define HWN 4096
#define QB 64            // q per block; ALL 8 waves compute the same 64 q
#define KSPLIT 8         // each wave privately owns 512 k
#define KT 32
#define NITER (HWN / KSPLIT / KT)   // 16 chunks per wave
#define NKC (HWN / KT)              // 128 k-chunks per batch

typedef __attribute__((ext_vector_type(8))) short bf16x8;
typedef __attribute__((ext_vector_type(4))) float f32x4;

// precomputed bf16 operand layouts (written by prep_kernel every launch)
__device__ __align__(16) unsigned short g_bgT[4][HWN][CC];       // (bg*sb)^T [b][k][c]
__device__ __align__(16) unsigned short g_bgN[4][NKC][CC][KT];   // bf16(bg) chunk-major
__device__ __align__(16) unsigned short g_fgT[4][HWN][CC];       // (fg*sf)^T [b][q][c]

static __device__ __forceinline__ unsigned int f2bf(float x) {   // RNE
  union { float f; unsigned int u; } v; v.f = x;
  return (v.u + 0x7fffu + ((v.u >> 16) & 1u)) >> 16;
}
static __device__ __forceinline__ unsigned int packbf(float lo, float hi) {
  return f2bf(lo) | (f2bf(hi) << 16);
}

// ---- prep: fused column norms + bf16 operand layouts (identical to r8) ----
// grid 512 = which(2) x b(4) x ktile(64), 256 threads
__global__ __launch_bounds__(256) void prep_kernel(const float* __restrict__ bg,
                                                   const float* __restrict__ fg) {
  __shared__ float lds[64 * 65];   // [k][c], stride 65 (2-way banks everywhere)
  const int bid = blockIdx.x;
  const int kt = bid & 63, b = (bid >> 6) & 3, which = bid >> 8;
  const float* src = (which ? fg : bg) + (size_t)b * CC * HWN + kt * 64;
  const int tid = threadIdx.x;

  // stage tile transposed: thread loads [c][k-range] float4, writes lds[k][c]
  {
    int c = tid >> 2, k0 = (tid & 3) * 16;
#pragma unroll
    for (int j4 = 0; j4 < 4; ++j4) {
      float4 v = *(const float4*)(src + (size_t)c * HWN + k0 + 4 * j4);
      lds[(k0 + 4 * j4 + 0) * 65 + c] = v.x;
      lds[(k0 + 4 * j4 + 1) * 65 + c] = v.y;
      lds[(k0 + 4 * j4 + 2) * 65 + c] = v.z;
      lds[(k0 + 4 * j4 + 3) * 65 + c] = v.w;
    }
  }
  __syncthreads();

  const int k = tid >> 2, u = tid & 3;
  // column norm: 4 threads per k, each sums 16 c, combine via shfl
  float ss = 0.f;
#pragma unroll
  for (int j = 0; j < 16; ++j) {
    float v = lds[k * 65 + u * 16 + j];
    ss = fmaf(v, v, ss);
  }
  ss += __shfl_xor(ss, 1, 64);
  ss += __shfl_xor(ss, 2, 64);
  const float s = 1.0f / fmaxf(sqrtf(ss), 1e-12f);

  // write scaled transposed [b][k][c] bf16
  {
    unsigned int* gT32 = (unsigned int*)(which ? &g_fgT[0][0][0] : &g_bgT[0][0][0]);
    size_t R = (size_t)b * HWN + kt * 64 + k;
    unsigned int w8[8];
#pragma unroll
    for (int i = 0; i < 8; ++i) {
      int c2 = u * 16 + 2 * i;
      w8[i] = packbf(lds[k * 65 + c2] * s, lds[k * 65 + c2 + 1] * s);
    }
    *(uint4*)&gT32[R * 32 + u * 8]     = make_uint4(w8[0], w8[1], w8[2], w8[3]);
    *(uint4*)&gT32[R * 32 + u * 8 + 4] = make_uint4(w8[4], w8[5], w8[6], w8[7]);
  }

  // bg blocks also write raw cast, chunk-major: [b][kc][c][32]
  if (which == 0) {
    unsigned int* gN32 = (unsigned int*)&g_bgN[0][0][0][0];
    int cN = tid >> 2, vN = tid & 3;   // vN covers k = vN*16 .. +15 of this 64-k tile
    unsigned int n8[8];
#pragma unroll
    for (int i = 0; i < 8; ++i) {
      int kk = vN * 16 + 2 * i;
      n8[i] = packbf(lds[kk * 65 + cN], lds[(kk + 1) * 65 + cN]);
    }
    int kc = kt * 2 + (vN >> 1);           // global chunk index within batch
    size_t RN = (((size_t)b * NKC + kc) * CC + cN) * (KT / 2) + (vN & 1) * 8;
    *(uint4*)&gN32[RN]     = make_uint4(n8[0], n8[1], n8[2], n8[3]);
    *(uint4*)&gN32[RN + 4] = make_uint4(n8[4], n8[5], n8[6], n8[7]);
  }
}

// ---- flash attention: r8 structure + 2-chunk-deep staging + qf-split PV ----
// r8 (best measured, attn~34us) was latency-bound on the per-chunk dependent
// chain at 2 waves/SIMD. This round, r8 byte-identical except:
//  (1) bgT staging 3-buffered, 2 chunks deep: issue loadN(it+1) -> stage(it+2)
//      -> vmcnt(12). Queue invariant: leftover {glds(it),loadN(it),glds(it+1)}
//      = 12, +8 issued = 20, wait 12 completes exactly chunk it's operands.
//      glds cover: 2 chunks (~10k cy >> 900 cy HBM). Tails: vmcnt(8)/vmcnt(0).
//  (2) softmax/PV split by qf pairs: SM(qf01)->P->PV(qf01) then SM(qf23)->
//      PV(qf23): qf23's exp/pack VALU fills PV01's lgkm-wait + MFMA shadow.
// LDS: [0,98304)        bgT staging, wave w: [w*12288 + {0,4096,8192})
//      [98304,139264)   P per wave [64q][40k] ushort (5120 B each)
//      [139264,141312)  mL [8ks][64q] f32
//      epilogue aliases [0,69632) as mO [8ks][64c][34] f32 (two q-half passes)
#define P_OFF 98304
#define ML_OFF 139264
#define SMEM_BYTES 141312
__global__ __launch_bounds__(512, 2) void attn_kernel(const float* __restrict__ fg,
                                                      const float* __restrict__ mask,
                                                      float* __restrict__ out) {
  __shared__ __align__(16) char smem[SMEM_BYTES];
  // bijective XCD swizzle (256 % 8 == 0): 2 XCDs per batch -> 2MB working set/L2
  const int wg = blockIdx.x;
  const int wgp = (wg & 7) * 32 + (wg >> 3);
  const int b = wgp >> 6;
  const int q0 = (wgp & 63) * QB;
  const int tid = threadIdx.x;
  const int lane = tid & 63;
  const int ks = tid >> 6;    // 0..7, private K-split (512 k each)
  const int m16 = lane & 15;
  const int quad = lane >> 4;

  // fg B-fragments (64 q), loaded once from global (L2)
  bf16x8 Bf[4][2];
#pragma unroll
  for (int qf = 0; qf < 4; ++qf)
#pragma unroll
    for (int h = 0; h < 2; ++h)
      Bf[qf][h] = *(const bf16x8*)&g_fgT[b][q0 + qf * 16 + m16][h * 32 + quad * 8];

  // bgT lane-swizzled staging sources (swizzle on global side; LDS lane-ordered)
  const unsigned short* srcT[4];
#pragma unroll
  for (int t = 0; t < 4; ++t) {
    int uT = t * 64 + lane;
    int kk = uT >> 3, pos = uT & 7, j = pos ^ (kk & 7);
    srcT[t] = &g_bgT[b][ks * 512 + kk][j * 8];
  }

  // bgN per-lane base (chunk-major): chunk block ks*16, row c=m16, k-slice quad*8
  const unsigned short* pN = &g_bgN[b][ks * 16][m16][quad * 8];

  unsigned short* P = (unsigned short*)(smem + P_OFF + ks * 5120);  // [64 q][40 k]
  float* mL = (float*)(smem + ML_OFF);

  float l_run[4] = {0.f, 0.f, 0.f, 0.f};   // per-lane partial sums per q-frag
  f32x4 O[4][4];                            // [c-tile][q-frag]
#pragma unroll
  for (int t = 0; t < 4; ++t)
#pragma unroll
    for (int qf = 0; qf < 4; ++qf) O[t][qf] = (f32x4){0.f, 0.f, 0.f, 0.f};

  char* const myT = smem + ks * 12288;      // this wave's bgT staging (3 x 4KB)

  auto stageT = [&](int bufoff) {
#pragma unroll
    for (int t = 0; t < 4; ++t) {
      __builtin_amdgcn_global_load_lds(
          (const __attribute__((address_space(1))) unsigned int*)srcT[t],
          (__attribute__((address_space(3))) unsigned int*)(myT + bufoff + t * 1024),
          16, 0, 0);
      srcT[t] += KT * CC;   // next chunk
    }
  };

  bf16x8 A0r[4], A1r[4];   // bgN register double-buffer (static-indexed)
  auto loadN = [&](bf16x8 (&A)[4], int ch) {
#pragma unroll
    for (int t = 0; t < 4; ++t)
      A[t] = *(const bf16x8*)(pN + (size_t)ch * (CC * KT) + t * 16 * KT);
  };

  // softmax for one q-frag: fixed-max (cosines, |s|<=1 -> p=exp(s-1)), pack P
  auto softmaxQ = [&](const f32x4 (&S)[4][2], int qf) {
#pragma unroll
    for (int i = 0; i < 2; ++i) {
      float pe[4];
#pragma unroll
      for (int r = 0; r < 4; ++r) {
        pe[r] = __expf(S[qf][i][r] - 1.0f);
        l_run[qf] += pe[r];
      }
      union { float f; unsigned int u; } x0, x1, x2, x3;
      x0.f = pe[0]; x1.f = pe[1]; x2.f = pe[2]; x3.f = pe[3];
      unsigned int p01 = __builtin_amdgcn_perm(x1.u + 0x8000u, x0.u + 0x8000u, 0x07060302u);
      unsigned int p23 = __builtin_amdgcn_perm(x3.u + 0x8000u, x2.u + 0x8000u, 0x07060302u);
      *(uint2*)&P[(qf * 16 + m16) * 40 + 16 * i + quad * 4] = make_uint2(p01, p23);
    }
  };

  int sA = 0, sB = 4096, sC = 8192;   // staging bufs: chunk it, it+1, it+2

  // one pipeline step: compute chunk `it` from buf sA + regs Ac, prefetching
  // bgN(it+1) into An and bgT(it+2) into sC. Issue order loadN -> stage keeps
  // the vmcnt queue so wait(12) completes exactly {glds(it), loadN(it)}.
  auto iter = [&](int it, bf16x8 (&Ac)[4], bf16x8 (&An)[4]) {
    if (it + 1 < NITER) loadN(An, it + 1);     // 4 x global_load_dwordx4
    if (it + 2 < NITER) {
      stageT(sC);                              // 4 x global_load_lds
      asm volatile("s_waitcnt vmcnt(12)" ::: "memory");
    } else if (it + 1 < NITER) {
      asm volatile("s_waitcnt vmcnt(8)" ::: "memory");
    } else {
      asm volatile("s_waitcnt vmcnt(0)" ::: "memory");
    }

    const char* baseT = myT + sA;

    // QK: S[32k][64q] = (bg*sb)^T · (fg*sf): 4 ds_read feed 16 MFMA
    f32x4 S[4][2];
    __builtin_amdgcn_s_setprio(1);
#pragma unroll
    for (int i = 0; i < 2; ++i) {
      int kk = 16 * i + m16;
      bf16x8 T0 = *(const bf16x8*)(baseT + kk * 128 + ((quad) ^ (kk & 7)) * 16);
      bf16x8 T1 = *(const bf16x8*)(baseT + kk * 128 + ((4 + quad) ^ (kk & 7)) * 16);
#pragma unroll
      for (int qf = 0; qf < 4; ++qf) {
        f32x4 acc = {0.f, 0.f, 0.f, 0.f};
        acc = __builtin_amdgcn_mfma_f32_16x16x32_bf16(T0, Bf[qf][0], acc, 0, 0, 0);
        acc = __builtin_amdgcn_mfma_f32_16x16x32_bf16(T1, Bf[qf][1], acc, 0, 0, 0);
        S[qf][i] = acc;
      }
    }
    __builtin_amdgcn_s_setprio(0);

    // ---- half A: softmax qf0,1 -> P -> PV qf0,1 ----
    softmaxQ(S, 0);
    softmaxQ(S, 1);
    {
      bf16x8 Pf0 = *(const bf16x8*)&P[(0 * 16 + m16) * 40 + quad * 8];
      bf16x8 Pf1 = *(const bf16x8*)&P[(1 * 16 + m16) * 40 + quad * 8];
      __builtin_amdgcn_s_setprio(1);
#pragma unroll
      for (int t = 0; t < 4; ++t) {
        O[t][0] = __builtin_amdgcn_mfma_f32_16x16x32_bf16(Ac[t], Pf0, O[t][0], 0, 0, 0);
        O[t][1] = __builtin_amdgcn_mfma_f32_16x16x32_bf16(Ac[t], Pf1, O[t][1], 0, 0, 0);
      }
      __builtin_amdgcn_s_setprio(0);
    }
    // ---- half B: softmax qf2,3 (fills PV01's MFMA/lgkm shadow) -> PV qf2,3 ----
    softmaxQ(S, 2);
    softmaxQ(S, 3);
    {
      bf16x8 Pf2 = *(const bf16x8*)&P[(2 * 16 + m16) * 40 + quad * 8];
      bf16x8 Pf3 = *(const bf16x8*)&P[(3 * 16 + m16) * 40 + quad * 8];
      __builtin_amdgcn_s_setprio(1);
#pragma unroll
      for (int t = 0; t < 4; ++t) {
        O[t][2] = __builtin_amdgcn_mfma_f32_16x16x32_bf16(Ac[t], Pf2, O[t][2], 0, 0, 0);
        O[t][3] = __builtin_amdgcn_mfma_f32_16x16x32_bf16(Ac[t], Pf3, O[t][3], 0, 0, 0);
      }
      __builtin_amdgcn_s_setprio(0);
    }

    int tmp = sA; sA = sB; sB = sC; sC = tmp;   // rotate staging bufs
  };

  // prologue: glds(0), loadN(0), glds(1) in flight (queue order matters)
  stageT(sA);
  loadN(A0r, 0);
  stageT(sB);

  for (int it2 = 0; it2 < NITER; it2 += 2) {
    iter(it2,     A0r, A1r);
    iter(it2 + 1, A1r, A0r);
  }

  // ---- merge 8 K-splits + epilogue (two q-half passes; mO aliases staging) ----
#pragma unroll
  for (int qf = 0; qf < 4; ++qf) {
    l_run[qf] += __shfl_xor(l_run[qf], 16, 64);
    l_run[qf] += __shfl_xor(l_run[qf], 32, 64);
  }
  if (quad == 0) {
#pragma unroll
    for (int qf = 0; qf < 4; ++qf) mL[ks * 64 + qf * 16 + m16] = l_run[qf];
  }
  float* mO = (float*)smem;   // [8 ks][64 c][34]
  const float* fgB = fg + (size_t)b * CC * HWN;
  const float* mk = mask + (size_t)b * HWN;
  float* outB = out + (size_t)b * CC * HWN;

#pragma unroll
  for (int half = 0; half < 2; ++half) {
    __syncthreads();   // pass 0: all waves done with staging/P reads; pass 1: reduce done
#pragma unroll
    for (int qh = 0; qh < 2; ++qh) {
      int qf = half * 2 + qh;
#pragma unroll
      for (int t = 0; t < 4; ++t)
#pragma unroll
        for (int r = 0; r < 4; ++r)
          mO[(ks * 64 + 16 * t + quad * 4 + r) * 34 + qh * 16 + m16] = O[t][qf][r];
    }
    __syncthreads();
    {
      int q = tid & 31, cb = tid >> 5;   // cb 0..15
      int qglob = q0 + half * 32 + q;
      float L = 0.f;
#pragma unroll
      for (int s = 0; s < 8; ++s) L += mL[s * 64 + half * 32 + q];
      float invL = 1.0f / L;
      float mv = mk[qglob];
#pragma unroll
      for (int e = 0; e < 4; ++e) {
        int c = cb * 4 + e;
        float acc = 0.f;
#pragma unroll
        for (int s = 0; s < 8; ++s) acc += mO[(s * 64 + c) * 34 + q];
        float att = acc * invL;
        float fgv = fgB[(size_t)c * HWN + qglob];
        outB[(size_t)c * HWN + qglob] = fgv + mv * (att - fgv);
      }
    }
  }
}

extern "C" void kernel_launch(void* const* d_in, const int* in_sizes, int n_in,
                              void* d_out, int out_size, void* d_ws, size_t ws_size,
                              hipStream_t stream) {
  const float* background = (const float*)d_in[0];
  const float* foreground = (const float*)d_in[1];
  const float* mask       = (const float*)d_in[2];
  float* out = (float*)d_out;
  prep_kernel<<<512, 256, 0, stream>>>(background, foreground);
  attn_kernel<<<dim3(HWN / QB * 4), 512, 0, stream>>>(foreground, mask, out);
}

// Round 13
// 91.670 us; speedup vs baseline: 2.7957x; 1.0210x over previous
//
#include <hip/hip_runtime.h>
#include <math.h>

#define CC 64
#define HWN 4096
#define QB 64            // q per block; ALL 8 waves compute the same 64 q
#define KSPLIT 8         // each wave privately owns 512 k
#define KT 32
#define NITER (HWN / KSPLIT / KT)   // 16 chunks per wave
#define NKC (HWN / KT)              // 128 k-chunks per batch

typedef __attribute__((ext_vector_type(8))) short bf16x8;
typedef __attribute__((ext_vector_type(4))) float f32x4;

// precomputed bf16 operand layouts (written by prep_kernel every launch)
__device__ __align__(16) unsigned short g_bgT[4][HWN][CC];       // (bg*sb)^T [b][k][c]
__device__ __align__(16) unsigned short g_bgN[4][NKC][CC][KT];   // bf16(bg) chunk-major
__device__ __align__(16) unsigned short g_fgT[4][HWN][CC];       // (fg*sf)^T [b][q][c]

static __device__ __forceinline__ unsigned int f2bf(float x) {   // RNE
  union { float f; unsigned int u; } v; v.f = x;
  return (v.u + 0x7fffu + ((v.u >> 16) & 1u)) >> 16;
}
static __device__ __forceinline__ unsigned int packbf(float lo, float hi) {
  return f2bf(lo) | (f2bf(hi) << 16);
}

// ---- prep v2: 2x parallelism (16 waves/CU) ----
// grid 1024 = which(2) x b(4) x kc(128), 256 threads; each block = 32k x 64c
// tile (= exactly one bgN chunk). Norm: 8 threads/k x 8 c + shfl_xor{1,2,4}.
// All LDS patterns <=2-way bank aliasing (stride 65).
__global__ __launch_bounds__(256) void prep_kernel(const float* __restrict__ bg,
                                                   const float* __restrict__ fg) {
  __shared__ float lds[32 * 65];   // [k][c]
  const int bid = blockIdx.x;
  const int kc = bid & 127, b = (bid >> 7) & 3, which = bid >> 9;
  const float* src = (which ? fg : bg) + (size_t)b * CC * HWN + kc * KT;
  const int tid = threadIdx.x;

  // stage tile transposed: thread (c = tid>>2, kq = tid&3) loads 2 float4
  {
    int c = tid >> 2, k0 = (tid & 3) * 8;
#pragma unroll
    for (int j4 = 0; j4 < 2; ++j4) {
      float4 v = *(const float4*)(src + (size_t)c * HWN + k0 + 4 * j4);
      lds[(k0 + 4 * j4 + 0) * 65 + c] = v.x;
      lds[(k0 + 4 * j4 + 1) * 65 + c] = v.y;
      lds[(k0 + 4 * j4 + 2) * 65 + c] = v.z;
      lds[(k0 + 4 * j4 + 3) * 65 + c] = v.w;
    }
  }
  __syncthreads();

  const int k = tid >> 3, u = tid & 7;
  // column norm: 8 threads per k, each sums 8 c, combine via shfl (in-wave)
  float ss = 0.f;
#pragma unroll
  for (int j = 0; j < 8; ++j) {
    float v = lds[k * 65 + u * 8 + j];
    ss = fmaf(v, v, ss);
  }
  ss += __shfl_xor(ss, 1, 64);
  ss += __shfl_xor(ss, 2, 64);
  ss += __shfl_xor(ss, 4, 64);
  const float s = 1.0f / fmaxf(sqrtf(ss), 1e-12f);

  // write scaled transposed [b][k][c] bf16: 8 threads/k, one uint4 (8 c) each
  {
    unsigned int* gT32 = (unsigned int*)(which ? &g_fgT[0][0][0] : &g_bgT[0][0][0]);
    size_t R = (size_t)b * HWN + kc * KT + k;
    unsigned int w4[4];
#pragma unroll
    for (int i = 0; i < 4; ++i) {
      int c2 = u * 8 + 2 * i;
      w4[i] = packbf(lds[k * 65 + c2] * s, lds[k * 65 + c2 + 1] * s);
    }
    *(uint4*)&gT32[R * 32 + u * 4] = make_uint4(w4[0], w4[1], w4[2], w4[3]);
  }

  // bg blocks also write raw cast, chunk-major [b][kc][c][32]: thread
  // (cN = tid>>2, vN = tid&3) writes 8 k at k = vN*8 (one uint4)
  if (which == 0) {
    unsigned int* gN32 = (unsigned int*)&g_bgN[0][0][0][0];
    int cN = tid >> 2, vN = tid & 3;
    unsigned int n4[4];
#pragma unroll
    for (int i = 0; i < 4; ++i) {
      int kk = vN * 8 + 2 * i;
      n4[i] = packbf(lds[kk * 65 + cN], lds[(kk + 1) * 65 + cN]);
    }
    size_t RN = (((size_t)b * NKC + kc) * CC + cN) * (KT / 2) + vN * 4;
    *(uint4*)&gN32[RN] = make_uint4(n4[0], n4[1], n4[2], n4[3]);
  }
}

// ---- flash attention: r8 exact (best measured: total 91.7us, attn ~34us) ----
// bgT via global_load_lds (4KB dbuf/wave), bgN chunk-major register dbuf,
// one vmcnt(8)/iter, zero loop barriers, XCD swizzle.
// LDS: [0,65536)        bgT staging, wave w: [w*8192 + buf*4096), swizzled
//      [65536,106496)   P per wave [64q][40k] ushort (5120 B each)
//      [106496,108544)  mL [8ks][64q] f32
//      epilogue aliases [0,69632) as mO [8ks][64c][34] f32 (two q-half passes)
#define P_OFF 65536
#define ML_OFF 106496
#define SMEM_BYTES 108544
__global__ __launch_bounds__(512, 2) void attn_kernel(const float* __restrict__ fg,
                                                      const float* __restrict__ mask,
                                                      float* __restrict__ out) {
  __shared__ __align__(16) char smem[SMEM_BYTES];
  // bijective XCD swizzle (256 % 8 == 0): 2 XCDs per batch -> 2MB working set/L2
  const int wg = blockIdx.x;
  const int wgp = (wg & 7) * 32 + (wg >> 3);
  const int b = wgp >> 6;
  const int q0 = (wgp & 63) * QB;
  const int tid = threadIdx.x;
  const int lane = tid & 63;
  const int ks = tid >> 6;    // 0..7, private K-split (512 k each)
  const int m16 = lane & 15;
  const int quad = lane >> 4;

  // fg B-fragments (64 q), loaded once from global (L2)
  bf16x8 Bf[4][2];
#pragma unroll
  for (int qf = 0; qf < 4; ++qf)
#pragma unroll
    for (int h = 0; h < 2; ++h)
      Bf[qf][h] = *(const bf16x8*)&g_fgT[b][q0 + qf * 16 + m16][h * 32 + quad * 8];

  // bgT lane-swizzled staging sources (swizzle on global side; LDS lane-ordered)
  const unsigned short* srcT[4];
#pragma unroll
  for (int t = 0; t < 4; ++t) {
    int uT = t * 64 + lane;
    int kk = uT >> 3, pos = uT & 7, j = pos ^ (kk & 7);
    srcT[t] = &g_bgT[b][ks * 512 + kk][j * 8];
  }

  // bgN per-lane base (chunk-major): chunk block ks*16, row c=m16, k-slice quad*8
  const unsigned short* pN = &g_bgN[b][ks * 16][m16][quad * 8];

  unsigned short* P = (unsigned short*)(smem + P_OFF + ks * 5120);  // [64 q][40 k]
  float* mL = (float*)(smem + ML_OFF);

  float l_run[4] = {0.f, 0.f, 0.f, 0.f};   // per-lane partial sums per q-frag
  f32x4 O[4][4];                            // [c-tile][q-frag]
#pragma unroll
  for (int t = 0; t < 4; ++t)
#pragma unroll
    for (int qf = 0; qf < 4; ++qf) O[t][qf] = (f32x4){0.f, 0.f, 0.f, 0.f};

  char* const myT = smem + ks * 8192;       // this wave's bgT staging (2 x 4KB)

  auto stageT = [&](int bufsel) {
#pragma unroll
    for (int t = 0; t < 4; ++t) {
      __builtin_amdgcn_global_load_lds(
          (const __attribute__((address_space(1))) unsigned int*)srcT[t],
          (__attribute__((address_space(3))) unsigned int*)(myT + bufsel * 4096 + t * 1024),
          16, 0, 0);
      srcT[t] += KT * CC;   // next chunk
    }
  };

  bf16x8 A0r[4], A1r[4];   // bgN register double-buffer (static-indexed)
  auto loadN = [&](bf16x8 (&A)[4], int ch) {
#pragma unroll
    for (int t = 0; t < 4; ++t)
      A[t] = *(const bf16x8*)(pN + (size_t)ch * (CC * KT) + t * 16 * KT);
  };

  // one pipeline step: compute chunk `it` from LDS buf `co` + regs Ac,
  // prefetching chunk it+1 into buf `co^1` + regs An.
  auto iter = [&](int it, int co, bf16x8 (&Ac)[4], bf16x8 (&An)[4]) {
    if (it + 1 < NITER) {
      stageT(co ^ 1);        // 4 x global_load_lds (bgT, chunk it+1)
      loadN(An, it + 1);     // 4 x global_load_dwordx4 (bgN, chunk it+1)
      // oldest-8 wait: chunk-it bgT glds AND chunk-it bgN reg loads complete
      asm volatile("s_waitcnt vmcnt(8)" ::: "memory");
    } else {
      asm volatile("s_waitcnt vmcnt(0)" ::: "memory");
    }

    const char* baseT = myT + co * 4096;

    // scores S[32k][64q] = (bg*sb)^T · (fg*sf): 4 ds_read feed 16 MFMA
    f32x4 S[4][2];
    __builtin_amdgcn_s_setprio(1);
#pragma unroll
    for (int i = 0; i < 2; ++i) {
      int kk = 16 * i + m16;
      bf16x8 T0 = *(const bf16x8*)(baseT + kk * 128 + ((quad) ^ (kk & 7)) * 16);
      bf16x8 T1 = *(const bf16x8*)(baseT + kk * 128 + ((4 + quad) ^ (kk & 7)) * 16);
#pragma unroll
      for (int qf = 0; qf < 4; ++qf) {
        f32x4 acc = {0.f, 0.f, 0.f, 0.f};
        acc = __builtin_amdgcn_mfma_f32_16x16x32_bf16(T0, Bf[qf][0], acc, 0, 0, 0);
        acc = __builtin_amdgcn_mfma_f32_16x16x32_bf16(T1, Bf[qf][1], acc, 0, 0, 0);
        S[qf][i] = acc;
      }
    }
    __builtin_amdgcn_s_setprio(0);

    // fixed-max softmax: cosines, |s| <= 1 -> p = exp(s-1); per-lane deferred sum
#pragma unroll
    for (int qf = 0; qf < 4; ++qf)
#pragma unroll
      for (int i = 0; i < 2; ++i) {
        float pe[4];
#pragma unroll
        for (int r = 0; r < 4; ++r) {
          pe[r] = __expf(S[qf][i][r] - 1.0f);
          l_run[qf] += pe[r];
        }
        // pack P -> per-wave LDS [q][k] bf16 (round-half-up via +0x8000, v_perm)
        union { float f; unsigned int u; } x0, x1, x2, x3;
        x0.f = pe[0]; x1.f = pe[1]; x2.f = pe[2]; x3.f = pe[3];
        unsigned int p01 = __builtin_amdgcn_perm(x1.u + 0x8000u, x0.u + 0x8000u, 0x07060302u);
        unsigned int p23 = __builtin_amdgcn_perm(x3.u + 0x8000u, x2.u + 0x8000u, 0x07060302u);
        *(uint2*)&P[(qf * 16 + m16) * 40 + 16 * i + quad * 4] = make_uint2(p01, p23);
      }

    // PV: O[c][q] += bg[c][k] · P[k][q]   (per-wave P + private regs: no barrier)
    bf16x8 Pf[4];
#pragma unroll
    for (int qf = 0; qf < 4; ++qf)
      Pf[qf] = *(const bf16x8*)&P[(qf * 16 + m16) * 40 + quad * 8];
    __builtin_amdgcn_s_setprio(1);
#pragma unroll
    for (int t = 0; t < 4; ++t)
#pragma unroll
      for (int qf = 0; qf < 4; ++qf)
        O[t][qf] = __builtin_amdgcn_mfma_f32_16x16x32_bf16(Ac[t], Pf[qf], O[t][qf], 0, 0, 0);
    __builtin_amdgcn_s_setprio(0);
  };

  // prologue: chunk 0 in flight (4 glds + 4 reg loads)
  stageT(0);
  loadN(A0r, 0);

  for (int it2 = 0; it2 < NITER; it2 += 2) {
    iter(it2,     0, A0r, A1r);
    iter(it2 + 1, 1, A1r, A0r);
  }

  // ---- merge 8 K-splits + epilogue (two q-half passes; mO aliases staging+P) ----
#pragma unroll
  for (int qf = 0; qf < 4; ++qf) {
    l_run[qf] += __shfl_xor(l_run[qf], 16, 64);
    l_run[qf] += __shfl_xor(l_run[qf], 32, 64);
  }
  if (quad == 0) {
#pragma unroll
    for (int qf = 0; qf < 4; ++qf) mL[ks * 64 + qf * 16 + m16] = l_run[qf];
  }
  float* mO = (float*)smem;   // [8 ks][64 c][34]
  const float* fgB = fg + (size_t)b * CC * HWN;
  const float* mk = mask + (size_t)b * HWN;
  float* outB = out + (size_t)b * CC * HWN;

#pragma unroll
  for (int half = 0; half < 2; ++half) {
    __syncthreads();   // pass 0: all waves done with staging/P reads; pass 1: reduce done
#pragma unroll
    for (int qh = 0; qh < 2; ++qh) {
      int qf = half * 2 + qh;
#pragma unroll
      for (int t = 0; t < 4; ++t)
#pragma unroll
        for (int r = 0; r < 4; ++r)
          mO[(ks * 64 + 16 * t + quad * 4 + r) * 34 + qh * 16 + m16] = O[t][qf][r];
    }
    __syncthreads();
    {
      int q = tid & 31, cb = tid >> 5;   // cb 0..15
      int qglob = q0 + half * 32 + q;
      float L = 0.f;
#pragma unroll
      for (int s = 0; s < 8; ++s) L += mL[s * 64 + half * 32 + q];
      float invL = 1.0f / L;
      float mv = mk[qglob];
#pragma unroll
      for (int e = 0; e < 4; ++e) {
        int c = cb * 4 + e;
        float acc = 0.f;
#pragma unroll
        for (int s = 0; s < 8; ++s) acc += mO[(s * 64 + c) * 34 + q];
        float att = acc * invL;
        float fgv = fgB[(size_t)c * HWN + qglob];
        outB[(size_t)c * HWN + qglob] = fgv + mv * (att - fgv);
      }
    }
  }
}

extern "C" void kernel_launch(void* const* d_in, const int* in_sizes, int n_in,
                              void* d_out, int out_size, void* d_ws, size_t ws_size,
                              hipStream_t stream) {
  const float* background = (const float*)d_in[0];
  const float* foreground = (const float*)d_in[1];
  const float* mask       = (const float*)d_in[2];
  float* out = (float*)d_out;
  prep_kernel<<<1024, 256, 0, stream>>>(background, foreground);
  attn_kernel<<<dim3(HWN / QB * 4), 512, 0, stream>>>(foreground, mask, out);
}